// Round 2
// baseline (970.654 us; speedup 1.0000x reference)
//
#include <hip/hip_runtime.h>

#define KQ   4096
#define NQ   8192
#define NTOK 91

#define W1 320
#define H1 96
#define HW1 30720
#define W2 160
#define H2 48
#define HW2 7680
#define W3 80
#define H3 24
#define HW3 1920
#define W4 40
#define H4 12
#define HW4 480

#define TWO_PI 6.28318530717958647692f

// ---------------- workspace layout (float offsets) ----------------
constexpr size_t WS_OFF = 0;                              // [NQ][16] learned offset rows
constexpr size_t WS_PC  = WS_OFF + (size_t)NQ * 16;       // [24][192] fixed-phi @ Wbot + w_loc_b
constexpr size_t WS_WT1 = WS_PC  + (size_t)24 * 192;      // [192][64]  w_loc_w[0:64]^T
constexpr size_t WS_WT2 = WS_WT1 + (size_t)192 * 64;      // [192][128] proj_l2_w^T
constexpr size_t WS_WT4 = WS_WT2 + (size_t)192 * 128;     // [192][384] proj_l4_w^T
constexpr size_t WS_L1P = WS_WT4 + (size_t)192 * 384;     // [2][HW1][192]
constexpr size_t WS_L2P = WS_L1P + (size_t)2 * HW1 * 192; // [2][HW2][192]
constexpr size_t WS_L3T = WS_L2P + (size_t)2 * HW2 * 192; // [2][HW3][192]
constexpr size_t WS_L4P = WS_L3T + (size_t)2 * HW3 * 192; // [2][HW4][192]
constexpr size_t WS_TOTAL = WS_L4P + (size_t)2 * HW4 * 192; // ~15.9M floats = 64 MB

// ---------------- helpers ----------------
__device__ __forceinline__ float gelu_f(float x) {
    return 0.5f * x * (1.0f + erff(x / 1.41421356237309504880f));
}

// Full per-sample bilinear setup (reference roundtrip + per-corner validity).
// Used for the center sample and the 8 learned (fractional) offsets.
__device__ __forceinline__ void bilin_setup(float px, float py, int W, int H, int SP,
                                            int* idx, float* wt) {
    float Wm1 = (float)(W - 1), Hm1 = (float)(H - 1);
    float nx = 2.0f * px / Wm1 - 1.0f;
    float ny = 2.0f * py / Hm1 - 1.0f;
    float x = (nx + 1.0f) * 0.5f * Wm1;
    float y = (ny + 1.0f) * 0.5f * Hm1;
    float x0f = floorf(x), y0f = floorf(y);
    float wx1 = x - x0f, wy1 = y - y0f;
    float wx0 = 1.0f - wx1, wy0 = 1.0f - wy1;
    int x0 = (int)x0f, y0 = (int)y0f;
    int x1 = x0 + 1, y1 = y0 + 1;
    bool vx0 = (x0 >= 0) && (x0 < W), vx1 = (x1 >= 0) && (x1 < W);
    bool vy0 = (y0 >= 0) && (y0 < H), vy1 = (y1 >= 0) && (y1 < H);
    int x0c = min(max(x0, 0), W - 1), x1c = min(max(x1, 0), W - 1);
    int y0c = min(max(y0, 0), H - 1), y1c = min(max(y1, 0), H - 1);
    idx[0] = (y0c * W + x0c) * SP;  wt[0] = (vx0 && vy0) ? wx0 * wy0 : 0.0f;
    idx[1] = (y0c * W + x1c) * SP;  wt[1] = (vx1 && vy0) ? wx1 * wy0 : 0.0f;
    idx[2] = (y1c * W + x0c) * SP;  wt[2] = (vx0 && vy1) ? wx0 * wy1 : 0.0f;
    idx[3] = (y1c * W + x1c) * SP;  wt[3] = (vx1 && vy1) ? wx1 * wy1 : 0.0f;
}

// Base-only setup for integer-offset grids: shared fractional weights + int corner.
__device__ __forceinline__ void bilin_base(float px, float py, int W, int H,
                                           int* x0, int* y0, float* w4) {
    float Wm1 = (float)(W - 1), Hm1 = (float)(H - 1);
    float nx = 2.0f * px / Wm1 - 1.0f;
    float ny = 2.0f * py / Hm1 - 1.0f;
    float x = (nx + 1.0f) * 0.5f * Wm1;
    float y = (ny + 1.0f) * 0.5f * Hm1;
    float x0f = floorf(x), y0f = floorf(y);
    float wx1 = x - x0f, wy1 = y - y0f;
    float wx0 = 1.0f - wx1, wy0 = 1.0f - wy1;
    *x0 = (int)x0f; *y0 = (int)y0f;
    w4[0] = wx0 * wy0; w4[1] = wx1 * wy0; w4[2] = wx0 * wy1; w4[3] = wx1 * wy1;
}

// Stage an ncell-cell patch (nx cells per row, origin (xs,ys)) of a channel-last
// map into LDS; OOB cells -> 0 (reproduces zero-padding since weights hit zeros).
__device__ __forceinline__ void stage_patch(const float* __restrict__ mb, int W, int H,
                                            int xs, int ys, int nx, int ncell,
                                            int tid, float (*patch)[200]) {
    for (int i = tid; i < ncell * 48; i += 256) {
        int cell = i / 48, o4 = i - cell * 48;
        int dy = cell / nx, dx = cell - nx * dy;
        int yy = ys + dy, xx = xs + dx;
        float4 v = make_float4(0.f, 0.f, 0.f, 0.f);
        if (xx >= 0 && xx < W && yy >= 0 && yy < H)
            v = *(const float4*)(mb + (size_t)(yy * W + xx) * 192 + o4 * 4);
        *(float4*)&patch[cell][o4 * 4] = v;
    }
}

// ---------------- K0: transpose the three projection weights ----------------
__global__ __launch_bounds__(256) void wt_kernel(const float* __restrict__ w_loc_w,
                                                 const float* __restrict__ pl2w,
                                                 const float* __restrict__ pl4w,
                                                 float* __restrict__ ws) {
    int i = blockIdx.x * 256 + threadIdx.x;
    if (i < 192 * 64) {
        int o = i >> 6, c = i & 63;
        ws[WS_WT1 + i] = w_loc_w[c * 192 + o];
    } else if (i < 192 * 64 + 192 * 128) {
        int j = i - 192 * 64;
        int o = j >> 7, c = j & 127;
        ws[WS_WT2 + j] = pl2w[c * 192 + o];
    } else if (i < 192 * 64 + 192 * 128 + 192 * 384) {
        int m = i - 192 * 64 - 192 * 128;
        int o = m / 384, c = m % 384;
        ws[WS_WT4 + m] = pl4w[c * 192 + o];
    }
}

// ---------------- K1: fixed-offset phi @ Wbot + w_loc_b -> pc[24][192] ----------------
__global__ __launch_bounds__(256) void pc_kernel(const float* __restrict__ w_loc_w,
                                                 const float* __restrict__ w_loc_b,
                                                 float* __restrict__ ws) {
    int i = blockIdx.x * 256 + threadIdx.x;
    if (i >= 24 * 192) return;
    int s = i / 192, o = i % 192;
    int p5 = s < 12 ? s : s + 1;               // skip center (0,0)
    float ox = (float)(p5 % 5 - 2), oy = (float)(p5 / 5 - 2);
    float acc = w_loc_b[o];
    #pragma unroll
    for (int j = 0; j < 4; ++j) {
        float fx = (float)(1 << j);
        acc = fmaf(sinf((ox * fx) * TWO_PI), w_loc_w[(64 + j) * 192 + o], acc);
        acc = fmaf(cosf((ox * fx) * TWO_PI), w_loc_w[(68 + j) * 192 + o], acc);
        acc = fmaf(sinf((oy * fx) * TWO_PI), w_loc_w[(72 + j) * 192 + o], acc);
        acc = fmaf(cosf((oy * fx) * TWO_PI), w_loc_w[(76 + j) * 192 + o], acc);
    }
    ws[WS_PC + i] = acc;
}

// ---------------- K2: per-query center: seed + learned offsets ----------------
__global__ __launch_bounds__(64) void center_kernel(const float* __restrict__ feat_l1,
                                                    const float* __restrict__ coords,
                                                    const float* __restrict__ w_q_w,
                                                    const float* __restrict__ w_q_b,
                                                    const float* __restrict__ w_off_w,
                                                    const float* __restrict__ w_off_b,
                                                    float* __restrict__ seed,
                                                    float* __restrict__ ws) {
    int q = blockIdx.x, b = q / KQ, lane = threadIdx.x;
    __shared__ float v[96];
    float cx = coords[2 * q], cy = coords[2 * q + 1];
    int idx[4]; float wt[4];
    bilin_setup(cx * 0.25f, cy * 0.25f, W1, H1, 1, idx, wt);
    const float* f = feat_l1 + ((size_t)b * 64 + lane) * HW1;
    v[lane] = f[idx[0]] * wt[0] + f[idx[1]] * wt[1] + f[idx[2]] * wt[2] + f[idx[3]] * wt[3];
    if (lane < 32) {  // pe_q: [sin x(8), cos x(8), sin y(8), cos y(8)]
        int comp = lane >> 3, fr = lane & 7;
        float c = (comp < 2) ? (cx / 1280.0f) : (cy / 384.0f);
        float ang = (c * (float)(1 << fr)) * TWO_PI;
        v[64 + lane] = (comp & 1) ? cosf(ang) : sinf(ang);
    }
    __syncthreads();
    float a0 = 0.f, a1 = 0.f, a2 = 0.f;
    for (int k = 0; k < 96; ++k) {
        float vk = v[k];
        const float* wr = w_q_w + k * 192 + lane;
        a0 = fmaf(vk, wr[0], a0);
        a1 = fmaf(vk, wr[64], a1);
        a2 = fmaf(vk, wr[128], a2);
    }
    float* so = seed + (size_t)q * 192;
    so[lane]       = a0 + w_q_b[lane];
    so[lane + 64]  = a1 + w_q_b[lane + 64];
    so[lane + 128] = a2 + w_q_b[lane + 128];
    if (lane < 16) {
        float acc = w_off_b[lane];
        for (int k = 0; k < 64; ++k) acc = fmaf(v[k], w_off_w[k * 16 + lane], acc);
        ws[WS_OFF + (size_t)q * 16 + lane] = 6.0f * tanhf(acc);
    }
}

// ---------------- K3/K4/K6: channel projection, output channel-last ----------------
// out[b][p][o] = sum_c feat[b][c][p] * W[c][o]   (no bias!)
template <int C, int NP>
__global__ __launch_bounds__(256) void proj_kernel(const float* __restrict__ feat,
                                                   const float* __restrict__ wT, // [192][C]
                                                   float* __restrict__ outp,     // [B][HW][192]
                                                   int HW) {
    __shared__ __align__(16) float AT[NP][C + 4];
    int b = blockIdx.y;
    int p0 = blockIdx.x * NP;
    int tid = threadIdx.x;
    const float* fb = feat + (size_t)b * C * HW + p0;
    for (int i = tid; i < C * NP; i += 256) {
        int c = i / NP, p = i % NP;  // NP is pow2
        AT[p][c] = fb[(size_t)c * HW + p];
    }
    __syncthreads();
    constexpr int PG = NP / 8;
    int og = tid & 31, pg = tid >> 5, o0 = og * 6;
    const float* w0 = wT + (size_t)o0 * C;
    float acc[PG][6];
    #pragma unroll
    for (int j = 0; j < PG; ++j)
        #pragma unroll
        for (int i2 = 0; i2 < 6; ++i2) acc[j][i2] = 0.f;
    for (int c4 = 0; c4 < C; c4 += 4) {
        float4 w[6];
        #pragma unroll
        for (int i2 = 0; i2 < 6; ++i2) w[i2] = *(const float4*)(w0 + i2 * C + c4);
        #pragma unroll
        for (int j = 0; j < PG; ++j) {
            float4 a = *(const float4*)&AT[pg * PG + j][c4];
            #pragma unroll
            for (int i2 = 0; i2 < 6; ++i2) {
                acc[j][i2] = fmaf(a.x, w[i2].x, acc[j][i2]);
                acc[j][i2] = fmaf(a.y, w[i2].y, acc[j][i2]);
                acc[j][i2] = fmaf(a.z, w[i2].z, acc[j][i2]);
                acc[j][i2] = fmaf(a.w, w[i2].w, acc[j][i2]);
            }
        }
    }
    #pragma unroll
    for (int j = 0; j < PG; ++j) {
        float* op = outp + ((size_t)b * HW + p0 + pg * PG + j) * 192 + o0;
        #pragma unroll
        for (int i2 = 0; i2 < 6; ++i2) op[i2] = acc[j][i2];
    }
}

// ---------------- K5: feat_l3 [B,192,HW3] -> channel-last [B,HW3,192] ----------------
__global__ __launch_bounds__(256) void trans_l3_kernel(const float* __restrict__ in,
                                                       float* __restrict__ outp) {
    __shared__ float tile[32][33];
    int b = blockIdx.z;
    int p0 = blockIdx.x * 32, c0 = blockIdx.y * 32;
    int tx = threadIdx.x & 31, ty = threadIdx.x >> 5;
    const float* ip = in + (size_t)b * 192 * HW3;
    #pragma unroll
    for (int i = ty; i < 32; i += 8)
        tile[i][tx] = ip[(size_t)(c0 + i) * HW3 + p0 + tx];
    __syncthreads();
    float* op = outp + (size_t)b * HW3 * 192;
    #pragma unroll
    for (int i = ty; i < 32; i += 8)
        op[(size_t)(p0 + i) * 192 + c0 + tx] = tile[tx][i];
}

// ---------------- K7: l1 tokens (24 fixed via LDS patch + 8 learned direct) ----------------
__global__ __launch_bounds__(256) void l1tok_kernel(const float* __restrict__ ws,
                                                    const float* __restrict__ coords,
                                                    const float* __restrict__ w_loc_w,
                                                    const float* __restrict__ w_loc_b,
                                                    const float* __restrict__ e_l1,
                                                    float* __restrict__ tok) {
    int q = blockIdx.x, b = q / KQ, tid = threadIdx.x;
    __shared__ float patch[36][200];
    __shared__ float wb[16 * 192];
    __shared__ float phis[8][16];
    __shared__ int   si[8][4];
    __shared__ float sw[8][4];
    for (int i = tid; i < 16 * 192; i += 256) wb[i] = w_loc_w[64 * 192 + i];
    float cx = coords[2 * q] * 0.25f, cyc = coords[2 * q + 1] * 0.25f;
    if (tid < 8) {
        float ox = ws[WS_OFF + (size_t)q * 16 + tid * 2 + 0];
        float oy = ws[WS_OFF + (size_t)q * 16 + tid * 2 + 1];
        bilin_setup(cx + ox, cyc + oy, W1, H1, 192, si[tid], sw[tid]);
    } else if (tid < 16) {
        int li = tid - 8;
        float ox = ws[WS_OFF + (size_t)q * 16 + li * 2 + 0];
        float oy = ws[WS_OFF + (size_t)q * 16 + li * 2 + 1];
        #pragma unroll
        for (int j2 = 0; j2 < 4; ++j2) {
            float fx = (float)(1 << j2);
            phis[li][j2]      = sinf((ox * fx) * TWO_PI);
            phis[li][4 + j2]  = cosf((ox * fx) * TWO_PI);
            phis[li][8 + j2]  = sinf((oy * fx) * TWO_PI);
            phis[li][12 + j2] = cosf((oy * fx) * TWO_PI);
        }
    }
    int x0b, y0b; float w4[4];
    bilin_base(cx, cyc, W1, H1, &x0b, &y0b, w4);
    const float* mb = ws + WS_L1P + (size_t)b * HW1 * 192;
    stage_patch(mb, W1, H1, x0b - 2, y0b - 2, 6, 36, tid, patch);
    __syncthreads();
    int og = tid & 31, sg = tid >> 5, o0 = og * 6;
    float el[6], wl[6];
    #pragma unroll
    for (int i = 0; i < 6; ++i) { el[i] = e_l1[o0 + i]; wl[i] = w_loc_b[o0 + i]; }
    #pragma unroll
    for (int j = 0; j < 4; ++j) {
        int s = sg * 4 + j;   // waves 0-5: fixed, waves 6-7: learned (uniform branches)
        float z[6];
        if (s < 24) {
            int p5 = s < 12 ? s : s + 1;
            int cyp = p5 / 5, cxp = p5 - 5 * cyp;
            const float* p00 = &patch[cyp * 6 + cxp][o0];
            const float* p01 = &patch[cyp * 6 + cxp + 1][o0];
            const float* p10 = &patch[cyp * 6 + cxp + 6][o0];
            const float* p11 = &patch[cyp * 6 + cxp + 7][o0];
            const float* pcp = ws + WS_PC + (size_t)s * 192 + o0;
            #pragma unroll
            for (int i = 0; i < 6; ++i) {
                float zz = pcp[i];
                zz = fmaf(p00[i], w4[0], zz);
                zz = fmaf(p01[i], w4[1], zz);
                zz = fmaf(p10[i], w4[2], zz);
                zz = fmaf(p11[i], w4[3], zz);
                z[i] = zz;
            }
        } else {
            int li = s - 24;
            #pragma unroll
            for (int i = 0; i < 6; ++i) z[i] = 0.f;
            #pragma unroll
            for (int cn = 0; cn < 4; ++cn) {
                float w = sw[li][cn];
                const float* p = mb + si[li][cn] + o0;
                float2 v0 = *(const float2*)(p);
                float2 v1 = *(const float2*)(p + 2);
                float2 v2 = *(const float2*)(p + 4);
                z[0] = fmaf(v0.x, w, z[0]); z[1] = fmaf(v0.y, w, z[1]);
                z[2] = fmaf(v1.x, w, z[2]); z[3] = fmaf(v1.y, w, z[3]);
                z[4] = fmaf(v2.x, w, z[4]); z[5] = fmaf(v2.y, w, z[5]);
            }
            #pragma unroll
            for (int i = 0; i < 6; ++i) z[i] += wl[i];
            const float* ph = phis[li];
            #pragma unroll
            for (int k = 0; k < 16; ++k) {
                float pv = ph[k];
                const float* wr = wb + k * 192 + o0;
                #pragma unroll
                for (int i = 0; i < 6; ++i) z[i] = fmaf(pv, wr[i], z[i]);
            }
        }
        #pragma unroll
        for (int i = 0; i < 6; ++i) z[i] = gelu_f(z[i]) + el[i];
        float* op = tok + ((size_t)q * NTOK + s) * 192 + o0;
        *(float2*)(op)     = make_float2(z[0], z[1]);
        *(float2*)(op + 2) = make_float2(z[2], z[3]);
        *(float2*)(op + 4) = make_float2(z[4], z[5]);
    }
}

// ---------------- token grid compute from staged patch ----------------
__device__ __forceinline__ void tok_grid(const float (*patch)[200], const float* w4,
                                         const float* bias, const float* __restrict__ rpe,
                                         float* __restrict__ tok_q, int slot,
                                         int gs, int ns, int sg, int o0, bool l4rpe) {
    #pragma unroll
    for (int j = 0; j < 4; ++j) {
        int s = sg + 8 * j;
        if (s < ns) {
            int cy = s / gs, cx = s - gs * cy;
            int c00 = cy * (gs + 1) + cx;
            int rrow = l4rpe ? (cy * 5 + cx + 6) : s;
            const float* rp = rpe + (size_t)rrow * 192 + o0;
            const float* p00 = &patch[c00][o0];
            const float* p01 = &patch[c00 + 1][o0];
            const float* p10 = &patch[c00 + gs + 1][o0];
            const float* p11 = &patch[c00 + gs + 2][o0];
            float z[6];
            #pragma unroll
            for (int i = 0; i < 6; ++i) {
                float zz = bias[i] + rp[i];
                zz = fmaf(p00[i], w4[0], zz);
                zz = fmaf(p01[i], w4[1], zz);
                zz = fmaf(p10[i], w4[2], zz);
                zz = fmaf(p11[i], w4[3], zz);
                z[i] = zz;
            }
            float* op = tok_q + (size_t)(slot + s) * 192 + o0;
            *(float2*)(op)     = make_float2(z[0], z[1]);
            *(float2*)(op + 2) = make_float2(z[2], z[3]);
            *(float2*)(op + 4) = make_float2(z[4], z[5]);
        }
    }
}

// ---------------- K8: fused l2+l3+l4 tokens ----------------
__global__ __launch_bounds__(256) void l234tok_kernel(const float* __restrict__ ws,
                                                      const float* __restrict__ coords,
                                                      const float* __restrict__ pl2b,
                                                      const float* __restrict__ pl4b,
                                                      const float* __restrict__ e2,
                                                      const float* __restrict__ e3,
                                                      const float* __restrict__ e4,
                                                      const float* __restrict__ rpe,
                                                      float* __restrict__ tok) {
    int q = blockIdx.x, b = q / KQ, tid = threadIdx.x;
    __shared__ float patch[36][200];
    float cx = coords[2 * q], cyc = coords[2 * q + 1];
    int og = tid & 31, sg = tid >> 5, o0 = og * 6;
    float* tok_q = tok + (size_t)q * NTOK * 192;
    float bias[6];
    int x0b, y0b; float w4[4];

    // ---- level 2 (5x5, proj bias) ----
    bilin_base(cx * 0.125f, cyc * 0.125f, W2, H2, &x0b, &y0b, w4);
    stage_patch(ws + WS_L2P + (size_t)b * HW2 * 192, W2, H2, x0b - 2, y0b - 2, 6, 36, tid, patch);
    __syncthreads();
    #pragma unroll
    for (int i = 0; i < 6; ++i) bias[i] = pl2b[o0 + i] + e2[o0 + i];
    tok_grid(patch, w4, bias, rpe, tok_q, 32, 5, 25, sg, o0, false);
    __syncthreads();

    // ---- level 3 (5x5, no proj) ----
    bilin_base(cx * 0.0625f, cyc * 0.0625f, W3, H3, &x0b, &y0b, w4);
    stage_patch(ws + WS_L3T + (size_t)b * HW3 * 192, W3, H3, x0b - 2, y0b - 2, 6, 36, tid, patch);
    __syncthreads();
    #pragma unroll
    for (int i = 0; i < 6; ++i) bias[i] = e3[o0 + i];
    tok_grid(patch, w4, bias, rpe, tok_q, 57, 5, 25, sg, o0, false);
    __syncthreads();

    // ---- level 4 (3x3, proj bias, L4_RPE_IDX rows) ----
    bilin_base(cx * 0.03125f, cyc * 0.03125f, W4, H4, &x0b, &y0b, w4);
    stage_patch(ws + WS_L4P + (size_t)b * HW4 * 192, W4, H4, x0b - 1, y0b - 1, 4, 16, tid, patch);
    __syncthreads();
    #pragma unroll
    for (int i = 0; i < 6; ++i) bias[i] = pl4b[o0 + i] + e4[o0 + i];
    tok_grid(patch, w4, bias, rpe, tok_q, 82, 3, 9, sg, o0, true);
}

// ---------------- host ----------------
extern "C" void kernel_launch(void* const* d_in, const int* in_sizes, int n_in,
                              void* d_out, int out_size, void* d_ws, size_t ws_size,
                              hipStream_t stream) {
    const float* feat_l1   = (const float*)d_in[0];
    const float* feat_l2   = (const float*)d_in[1];
    const float* feat_l3   = (const float*)d_in[2];
    const float* feat_l4   = (const float*)d_in[3];
    const float* coords    = (const float*)d_in[4];
    const float* proj_l2_w = (const float*)d_in[5];
    const float* proj_l2_b = (const float*)d_in[6];
    const float* proj_l4_w = (const float*)d_in[7];
    const float* proj_l4_b = (const float*)d_in[8];
    const float* w_off_w   = (const float*)d_in[9];
    const float* w_off_b   = (const float*)d_in[10];
    const float* w_loc_w   = (const float*)d_in[11];
    const float* w_loc_b   = (const float*)d_in[12];
    const float* w_q_w     = (const float*)d_in[13];
    const float* w_q_b     = (const float*)d_in[14];
    const float* e_l1      = (const float*)d_in[15];
    const float* e_l2      = (const float*)d_in[16];
    const float* e_l3      = (const float*)d_in[17];
    const float* e_l4      = (const float*)d_in[18];
    const float* rpe       = (const float*)d_in[19];

    float* tok  = (float*)d_out;
    float* seed = tok + (size_t)NQ * NTOK * 192;
    float* ws   = (float*)d_ws;

    // prep: weight transposes, fixed-phi table, center (seed + learned offsets)
    wt_kernel<<<432, 256, 0, stream>>>(w_loc_w, proj_l2_w, proj_l4_w, ws);
    pc_kernel<<<18, 256, 0, stream>>>(w_loc_w, w_loc_b, ws);
    center_kernel<<<NQ, 64, 0, stream>>>(feat_l1, coords, w_q_w, w_q_b,
                                         w_off_w, w_off_b, seed, ws);

    // projected / transposed channel-last maps
    proj_kernel<64, 64><<<dim3(HW1 / 64, 2), 256, 0, stream>>>(feat_l1, ws + WS_WT1,
                                                               ws + WS_L1P, HW1);
    proj_kernel<128, 64><<<dim3(HW2 / 64, 2), 256, 0, stream>>>(feat_l2, ws + WS_WT2,
                                                                ws + WS_L2P, HW2);
    trans_l3_kernel<<<dim3(HW3 / 32, 6, 2), 256, 0, stream>>>(feat_l3, ws + WS_L3T);
    proj_kernel<384, 32><<<dim3(HW4 / 32, 2), 256, 0, stream>>>(feat_l4, ws + WS_WT4,
                                                                ws + WS_L4P, HW4);

    // token gathers
    l1tok_kernel<<<NQ, 256, 0, stream>>>(ws, coords, w_loc_w, w_loc_b, e_l1, tok);
    l234tok_kernel<<<NQ, 256, 0, stream>>>(ws, coords, proj_l2_b, proj_l4_b,
                                           e_l2, e_l3, e_l4, rpe, tok);
}